// Round 2
// baseline (432.241 us; speedup 1.0000x reference)
//
#include <hip/hip_runtime.h>

// Blockwise 8x8 2D orthonormal DCT:
//   x: (64, 1, 1024, 1024) fp32  ->  out: (64, 64, 128, 128) fp32
//   out[n][i*8+j][gi][gj] = (A · block · A^T)[i][j]
//
// Memory-bound (512 MB traffic). One thread per 8x8 tile, fast DCT-8
// butterfly with compile-time constants (7 distinct magnitudes -> SGPRs,
// signs folded into FMA modifiers). No LDS, ~100 VGPRs -> 4 waves/SIMD.

#define BS   8
#define HW   1024
#define GH   128
#define GW   128
#define NIMG 64

// Orthonormal 8-point DCT-II, decomposed even/odd (derived from
// A[i][n] = 0.5*c_i*cos((2n+1)*i*pi/16), c_0 = 1/sqrt(2)).
__device__ __forceinline__ void dct8(const float x[8], float X[8]) {
    const float s0 = x[0] + x[7], s1 = x[1] + x[6];
    const float s2 = x[2] + x[5], s3 = x[3] + x[4];
    const float d0 = x[0] - x[7], d1 = x[1] - x[6];
    const float d2 = x[2] - x[5], d3 = x[3] - x[4];

    const float C0  = 0.35355339059327373f;   // 1/(2*sqrt(2))
    const float C2a = 0.46193976625564337f;   // 0.5*cos(pi/8)
    const float C2b = 0.19134171618254492f;   // 0.5*sin(pi/8)
    const float O0  = 0.49039264020161522f;   // 0.5*cos(pi/16)
    const float O1  = 0.41573480615127262f;   // 0.5*cos(3pi/16)
    const float O2  = 0.27778511650980114f;   // 0.5*cos(5pi/16)
    const float O3  = 0.09754516100806417f;   // 0.5*cos(7pi/16)

    X[0] = C0 * ((s0 + s3) + (s1 + s2));
    X[4] = C0 * ((s0 + s3) - (s1 + s2));
    X[2] = C2a * (s0 - s3) + C2b * (s1 - s2);
    X[6] = C2b * (s0 - s3) - C2a * (s1 - s2);
    X[1] =  O0 * d0 + O1 * d1 + O2 * d2 + O3 * d3;
    X[3] =  O1 * d0 - O3 * d1 - O0 * d2 - O2 * d3;
    X[5] =  O2 * d0 - O0 * d1 + O3 * d2 + O1 * d3;
    X[7] =  O3 * d0 - O2 * d1 + O1 * d2 - O0 * d3;
}

__global__ __launch_bounds__(256, 4) void dct2d_kernel(
        const float* __restrict__ x,
        float* __restrict__ out) {
    const int id  = blockIdx.x * 256 + threadIdx.x;  // [0, 64*128*128)
    const int n   = id >> 14;                        // / (128*128)
    const int rem = id & 16383;
    const int gi  = rem >> 7;                        // / 128
    const int gj  = rem & 127;

    const float* xp = x + (size_t)n * (HW * HW) + (size_t)(gi * BS) * HW + gj * BS;

    // Row pass: t[k][j] = (block @ A^T)[k][j]
    float t[8][8];
    #pragma unroll
    for (int k = 0; k < 8; ++k) {
        const float4 lo = *(const float4*)(xp + (size_t)k * HW);
        const float4 hi = *(const float4*)(xp + (size_t)k * HW + 4);
        const float row[8] = {lo.x, lo.y, lo.z, lo.w, hi.x, hi.y, hi.z, hi.w};
        dct8(row, t[k]);
    }

    // Column pass: coeff[i][j] = (A @ t)[i][j]; store channel-major.
    float* op = out + (size_t)n * (64 * GH * GW) + (size_t)gi * GW + gj;
    #pragma unroll
    for (int j = 0; j < 8; ++j) {
        const float col[8] = {t[0][j], t[1][j], t[2][j], t[3][j],
                              t[4][j], t[5][j], t[6][j], t[7][j]};
        float o[8];
        dct8(col, o);
        #pragma unroll
        for (int i = 0; i < 8; ++i) {
            op[(size_t)(i * 8 + j) * (GH * GW)] = o[i];
        }
    }
}

extern "C" void kernel_launch(void* const* d_in, const int* in_sizes, int n_in,
                              void* d_out, int out_size, void* d_ws, size_t ws_size,
                              hipStream_t stream) {
    const float* x = (const float*)d_in[0];
    float* out     = (float*)d_out;

    const int total_threads = NIMG * GH * GW;       // 1,048,576
    const int block = 256;
    const int grid  = total_threads / block;        // 4096 (exact)
    dct2d_kernel<<<grid, block, 0, stream>>>(x, out);
}